// Round 2
// baseline (306.788 us; speedup 1.0000x reference)
//
#include <hip/hip_runtime.h>

#define T_STEPS 512
#define NCH 64      // number of chunks
#define CHUNK 8     // timesteps per chunk (register gi buffer depth)

typedef float f32x4 __attribute__((ext_vector_type(4)));

__device__ __forceinline__ float rcp_fast(float x) {
    return __builtin_amdgcn_rcpf(x);
}

// broadcast quad-lane S's value to all 4 lanes of the quad (VALU DPP quad_perm)
template <int S>
__device__ __forceinline__ float qb(float v) {
    return __int_as_float(
        __builtin_amdgcn_mov_dpp(__float_as_int(v), S * 0x55, 0xF, 0xF, true));
}
template <int S>
__device__ __forceinline__ f32x4 qb4(f32x4 v) {
    f32x4 r;
    r.x = qb<S>(v.x); r.y = qb<S>(v.y); r.z = qb<S>(v.z); r.w = qb<S>(v.w);
    return r;
}

// quad butterfly sum
__device__ __forceinline__ float qsum(float p) {
    p += __int_as_float(__builtin_amdgcn_mov_dpp(__float_as_int(p), 0xB1, 0xF, 0xF, true));
    p += __int_as_float(__builtin_amdgcn_mov_dpp(__float_as_int(p), 0x4E, 0xF, 0xF, true));
    return p;
}

__device__ __forceinline__ float hsum4(f32x4 a) {
    return (a.x + a.z) + (a.y + a.w);
}

// feed-forward part: gi = W_ih . x_t + bias  (no h dependence -> full ILP)
__device__ __forceinline__ void bulk_step(
    f32x4 xq, const f32x4* wr4, const f32x4* wz4, const f32x4* wn4,
    float br, float bz, float bin,
    float& gr, float& gz, float& gn)
{
    f32x4 ar = {br, 0.f, 0.f, 0.f};
    f32x4 az = {bz, 0.f, 0.f, 0.f};
    f32x4 an = {bin, 0.f, 0.f, 0.f};
    {
        f32x4 b = qb4<0>(xq);
        ar = __builtin_elementwise_fma(wr4[0], b, ar);
        az = __builtin_elementwise_fma(wz4[0], b, az);
        an = __builtin_elementwise_fma(wn4[0], b, an);
    }
    {
        f32x4 b = qb4<1>(xq);
        ar = __builtin_elementwise_fma(wr4[1], b, ar);
        az = __builtin_elementwise_fma(wz4[1], b, az);
        an = __builtin_elementwise_fma(wn4[1], b, an);
    }
    {
        f32x4 b = qb4<2>(xq);
        ar = __builtin_elementwise_fma(wr4[2], b, ar);
        az = __builtin_elementwise_fma(wz4[2], b, az);
        an = __builtin_elementwise_fma(wn4[2], b, an);
    }
    {
        f32x4 b = qb4<3>(xq);
        ar = __builtin_elementwise_fma(wr4[3], b, ar);
        az = __builtin_elementwise_fma(wz4[3], b, az);
        an = __builtin_elementwise_fma(wn4[3], b, an);
    }
    gr = hsum4(ar);
    gz = hsum4(az);
    gn = hsum4(an);
}

// recurrent part: the only serial chain
__device__ __forceinline__ void scan_step(
    float& h, float gr, float gz, float gn,
    const float* ur, const float* uz, const float* un, float bhn)
{
    float h0 = qb<0>(h), h1 = qb<1>(h), h2 = qb<2>(h), h3 = qb<3>(h);
    gr = fmaf(ur[3], h3, fmaf(ur[2], h2, fmaf(ur[1], h1, fmaf(ur[0], h0, gr))));
    gz = fmaf(uz[3], h3, fmaf(uz[2], h2, fmaf(uz[1], h1, fmaf(uz[0], h0, gz))));
    float ghn = fmaf(un[3], h3, fmaf(un[2], h2, fmaf(un[1], h1, fmaf(un[0], h0, bhn))));
    float r = rcp_fast(1.0f + __expf(-gr));
    float z = rcp_fast(1.0f + __expf(-gz));
    float uu = fmaf(r, ghn, gn);
    float n = fmaf(-2.0f, rcp_fast(__expf(2.0f * uu) + 1.0f), 1.0f);
    h = fmaf(z, h - n, n);  // (1-z)*n + z*h
}

// One wave = 16 batch rows; quad lane j owns hidden unit j and gate rows
// {j, 4+j, 8+j}. 256 blocks x 64 thr -> 1 wave/CU on all 256 CUs.
// Software pipeline: body k scans chunk k (serial h chain) while computing
// chunk k+1's gi (pure ILP) and prefetching x for chunk k+2 (branch-free).
__global__ __launch_bounds__(64, 1) void gru_fused_kernel(
    const float* __restrict__ x,     // [B, T, 16]
    const float* __restrict__ w_ih,  // [12, 16]
    const float* __restrict__ w_hh,  // [12, 4]
    const float* __restrict__ b_ih,  // [12]
    const float* __restrict__ b_hh,  // [12]
    const float* __restrict__ fc_w,  // [1, 4]
    const float* __restrict__ fc_b,  // [1]
    float* __restrict__ out)         // [B]
{
    const int lane = threadIdx.x;
    const int q    = lane >> 2;
    const int j    = lane & 3;
    const int b    = blockIdx.x * 16 + q;

    // per-lane weights (w_ih rows j, 4+j, 8+j as float4 quads)
    f32x4 wr4[4], wz4[4], wn4[4];
#pragma unroll
    for (int s = 0; s < 4; ++s) {
        const float* pr = w_ih + (0 + j) * 16 + 4 * s;
        const float* pz = w_ih + (4 + j) * 16 + 4 * s;
        const float* pn = w_ih + (8 + j) * 16 + 4 * s;
        wr4[s] = f32x4{pr[0], pr[1], pr[2], pr[3]};
        wz4[s] = f32x4{pz[0], pz[1], pz[2], pz[3]};
        wn4[s] = f32x4{pn[0], pn[1], pn[2], pn[3]};
    }
    float ur[4], uz[4], un[4];
#pragma unroll
    for (int k = 0; k < 4; ++k) {
        ur[k] = w_hh[(0 + j) * 4 + k];
        uz[k] = w_hh[(4 + j) * 4 + k];
        un[k] = w_hh[(8 + j) * 4 + k];
    }
    const float br  = b_ih[0 + j] + b_hh[0 + j];
    const float bz  = b_ih[4 + j] + b_hh[4 + j];
    const float bin = b_ih[8 + j];   // n-gate input bias
    const float bhn = b_hh[8 + j];   // n-gate hidden bias (inside r* term)

    // lane's float4 slot of its row: x[b][t][4j..4j+3]
    const f32x4* xrow = (const f32x4*)x + ((size_t)b * T_STEPS) * 4 + j;

    f32x4 xbuf[CHUNK];
    float gi[2][3][CHUNK];   // ping-pong gi register buffers [r,z,n]
    float h = 0.0f;

    // prologue: load chunk 0, compute its gi into gi[0], reload xbuf = chunk 1
#pragma unroll
    for (int u = 0; u < CHUNK; ++u) xbuf[u] = xrow[(size_t)u * 4];
#pragma unroll
    for (int u = 0; u < CHUNK; ++u) {
        f32x4 xq = xbuf[u];
        xbuf[u] = xrow[(size_t)(CHUNK + u) * 4];
        bulk_step(xq, wr4, wz4, wn4, br, bz, bin,
                  gi[0][0][u], gi[0][1][u], gi[0][2][u]);
    }

#define BODY(IA, IB, KC)                                                      \
    {                                                                         \
        _Pragma("unroll")                                                     \
        for (int u = 0; u < CHUNK; ++u) {                                     \
            f32x4 xq = xbuf[u];                                               \
            int tl = (KC + 2) * CHUNK + u;                                    \
            tl = (tl > T_STEPS - 1) ? (T_STEPS - 1) : tl;  /* branch-free */  \
            xbuf[u] = xrow[(size_t)tl * 4];                                   \
            bulk_step(xq, wr4, wz4, wn4, br, bz, bin,                         \
                      gi[IB][0][u], gi[IB][1][u], gi[IB][2][u]);              \
            scan_step(h, gi[IA][0][u], gi[IA][1][u], gi[IA][2][u],            \
                      ur, uz, un, bhn);                                       \
        }                                                                     \
    }

    int k = 0;
#pragma unroll 1
    for (; k + 2 < NCH; k += 2) {   // bodies 0..61 in ping-pong pairs
        BODY(0, 1, k)
        BODY(1, 0, (k + 1))
    }
    BODY(0, 1, 62)                   // scan chunk 62, build chunk 63's gi
#undef BODY

    // final chunk: scan only
#pragma unroll
    for (int u = 0; u < CHUNK; ++u)
        scan_step(h, gi[1][0][u], gi[1][1][u], gi[1][2][u], ur, uz, un, bhn);

    // epilogue: out[b] = h . fc_w + fc_b
    float p = h * fc_w[j];
    p = qsum(p);
    if (j == 0) out[b] = p + fc_b[0];
}

extern "C" void kernel_launch(void* const* d_in, const int* in_sizes, int n_in,
                              void* d_out, int out_size, void* d_ws, size_t ws_size,
                              hipStream_t stream) {
    const float* x    = (const float*)d_in[0];
    const float* w_ih = (const float*)d_in[1];
    const float* w_hh = (const float*)d_in[2];
    const float* b_ih = (const float*)d_in[3];
    const float* b_hh = (const float*)d_in[4];
    const float* fc_w = (const float*)d_in[5];
    const float* fc_b = (const float*)d_in[6];
    float* out = (float*)d_out;

    const int B = out_size;      // 4096
    const int grid = B / 16;     // 16 batch rows per single-wave block
    gru_fused_kernel<<<grid, 64, 0, stream>>>(x, w_ih, w_hh, b_ih, b_hh, fc_w, fc_b, out);
}

// Round 3
// 202.715 us; speedup vs baseline: 1.5134x; 1.5134x over previous
//
#include <hip/hip_runtime.h>

#define T_STEPS 512
#define CHUNK   32      // timesteps per chunk
#define NCH     16      // 512/32 chunks
#define RING    64      // LDS ring depth in steps (2 chunks)

typedef float f32x4 __attribute__((ext_vector_type(4)));

__device__ __forceinline__ float rcp_fast(float x) {
    return __builtin_amdgcn_rcpf(x);
}

// broadcast quad-lane S's value to all 4 lanes of the quad (VALU DPP quad_perm)
template <int S>
__device__ __forceinline__ float qb(float v) {
    return __int_as_float(
        __builtin_amdgcn_mov_dpp(__float_as_int(v), S * 0x55, 0xF, 0xF, true));
}
template <int S>
__device__ __forceinline__ f32x4 qb4(f32x4 v) {
    f32x4 r;
    r.x = qb<S>(v.x); r.y = qb<S>(v.y); r.z = qb<S>(v.z); r.w = qb<S>(v.w);
    return r;
}

// quad butterfly sum
__device__ __forceinline__ float qsum(float p) {
    p += __int_as_float(__builtin_amdgcn_mov_dpp(__float_as_int(p), 0xB1, 0xF, 0xF, true));
    p += __int_as_float(__builtin_amdgcn_mov_dpp(__float_as_int(p), 0x4E, 0xF, 0xF, true));
    return p;
}

__device__ __forceinline__ float hsum4(f32x4 a) {
    return (a.x + a.z) + (a.y + a.w);
}

// feed-forward x-projection for one timestep (quad-split): no h dependence
__device__ __forceinline__ void bulk_step(
    f32x4 xq, const f32x4* wr4, const f32x4* wz4, const f32x4* wn4,
    float br, float bz, float bin,
    float& gr, float& gz, float& gn)
{
    f32x4 ar = {br, 0.f, 0.f, 0.f};
    f32x4 az = {bz, 0.f, 0.f, 0.f};
    f32x4 an = {bin, 0.f, 0.f, 0.f};
    {
        f32x4 bb = qb4<0>(xq);
        ar = __builtin_elementwise_fma(wr4[0], bb, ar);
        az = __builtin_elementwise_fma(wz4[0], bb, az);
        an = __builtin_elementwise_fma(wn4[0], bb, an);
    }
    {
        f32x4 bb = qb4<1>(xq);
        ar = __builtin_elementwise_fma(wr4[1], bb, ar);
        az = __builtin_elementwise_fma(wz4[1], bb, az);
        an = __builtin_elementwise_fma(wn4[1], bb, an);
    }
    {
        f32x4 bb = qb4<2>(xq);
        ar = __builtin_elementwise_fma(wr4[2], bb, ar);
        az = __builtin_elementwise_fma(wz4[2], bb, az);
        an = __builtin_elementwise_fma(wn4[2], bb, an);
    }
    {
        f32x4 bb = qb4<3>(xq);
        ar = __builtin_elementwise_fma(wr4[3], bb, ar);
        az = __builtin_elementwise_fma(wz4[3], bb, az);
        an = __builtin_elementwise_fma(wn4[3], bb, an);
    }
    gr = hsum4(ar);
    gz = hsum4(az);
    gn = hsum4(an);
}

// recurrent scan step — the only serial chain in the whole problem
__device__ __forceinline__ void scan_step(
    float& h, float gr, float gz, float gn,
    const float* ur, const float* uz, const float* un, float bhn)
{
    float h0 = qb<0>(h), h1 = qb<1>(h), h2 = qb<2>(h), h3 = qb<3>(h);
    gr = fmaf(ur[3], h3, fmaf(ur[2], h2, fmaf(ur[1], h1, fmaf(ur[0], h0, gr))));
    gz = fmaf(uz[3], h3, fmaf(uz[2], h2, fmaf(uz[1], h1, fmaf(uz[0], h0, gz))));
    float ghn = fmaf(un[3], h3, fmaf(un[2], h2, fmaf(un[1], h1, fmaf(un[0], h0, bhn))));
    float r = rcp_fast(1.0f + __expf(-gr));
    float z = rcp_fast(1.0f + __expf(-gz));
    float uu = fmaf(r, ghn, gn);
    float n = fmaf(-2.0f, rcp_fast(__expf(2.0f * uu) + 1.0f), 1.0f);
    h = fmaf(z, h - n, n);  // (1-z)*n + z*h
}

// Producer: compute gi for 16 consecutive steps starting at t0, batched loads.
__device__ __forceinline__ void produce16(
    int t0, const f32x4* __restrict__ xrow, f32x4* __restrict__ ring, int lane,
    const f32x4* wr4, const f32x4* wz4, const f32x4* wn4,
    float br, float bz, float bin)
{
    f32x4 xb[16];
#pragma unroll
    for (int i = 0; i < 16; ++i)
        xb[i] = xrow[(size_t)(t0 + i) * 4];   // all loads issued before any use
#pragma unroll
    for (int i = 0; i < 16; ++i) {
        float gr, gz, gn;
        bulk_step(xb[i], wr4, wz4, wn4, br, bz, bin, gr, gz, gn);
        ring[((t0 + i) & (RING - 1)) * 64 + lane] = f32x4{gr, gz, gn, 0.f};
    }
}

// Block = 3 waves x 64. Wave 0: scan consumer (16 batch rows, quad-split:
// lane quad q = row, lane j = hidden unit). Waves 1-2: x-projection
// producers filling a 2-chunk LDS ring. One barrier per 32-step chunk.
__global__ __launch_bounds__(192, 1) void gru_pc_kernel(
    const float* __restrict__ x,     // [B, T, 16]
    const float* __restrict__ w_ih,  // [12, 16]
    const float* __restrict__ w_hh,  // [12, 4]
    const float* __restrict__ b_ih,  // [12]
    const float* __restrict__ b_hh,  // [12]
    const float* __restrict__ fc_w,  // [1, 4]
    const float* __restrict__ fc_b,  // [1]
    float* __restrict__ out)         // [B]
{
    __shared__ f32x4 ring[RING * 64];   // 64 KB, lane-major: 2-way bank alias (free)

    const int tid  = threadIdx.x;
    const int wid  = tid >> 6;          // 0 = consumer, 1..2 = producers
    const int lane = tid & 63;
    const int q    = lane >> 2;         // row within block's 16
    const int j    = lane & 3;          // hidden unit / gate-row owner
    const int b    = blockIdx.x * 16 + q;

    if (wid == 0) {
        // ---------------- consumer: the serial scan ----------------
        float ur[4], uz[4], un[4];
#pragma unroll
        for (int k = 0; k < 4; ++k) {
            ur[k] = w_hh[(0 + j) * 4 + k];
            uz[k] = w_hh[(4 + j) * 4 + k];
            un[k] = w_hh[(8 + j) * 4 + k];
        }
        const float bhn = b_hh[8 + j];
        float h = 0.0f;

        __syncthreads();                 // chunk 0 ready
#pragma unroll 1
        for (int k = 0; k < NCH; ++k) {
            const int t0 = k * CHUNK;
            f32x4 gbuf[4];
#pragma unroll
            for (int p = 0; p < 4; ++p)
                gbuf[p] = ring[((t0 + p) & (RING - 1)) * 64 + lane];
#pragma unroll
            for (int u = 0; u < CHUNK; ++u) {
                f32x4 g = gbuf[u & 3];
                if (u < CHUNK - 4)       // compile-time per unrolled iter
                    gbuf[u & 3] = ring[((t0 + u + 4) & (RING - 1)) * 64 + lane];
                scan_step(h, g.x, g.y, g.z, ur, uz, un, bhn);
            }
            __syncthreads();             // chunk k consumed / chunk k+1 ready
        }

        float p = h * fc_w[j];
        p = qsum(p);
        if (j == 0) out[b] = p + fc_b[0];
    } else {
        // ---------------- producers: feed-forward x-projection ----------------
        f32x4 wr4[4], wz4[4], wn4[4];
#pragma unroll
        for (int s = 0; s < 4; ++s) {
            const float* pr = w_ih + (0 + j) * 16 + 4 * s;
            const float* pz = w_ih + (4 + j) * 16 + 4 * s;
            const float* pn = w_ih + (8 + j) * 16 + 4 * s;
            wr4[s] = f32x4{pr[0], pr[1], pr[2], pr[3]};
            wz4[s] = f32x4{pz[0], pz[1], pz[2], pz[3]};
            wn4[s] = f32x4{pn[0], pn[1], pn[2], pn[3]};
        }
        const float br  = b_ih[0 + j] + b_hh[0 + j];
        const float bz  = b_ih[4 + j] + b_hh[4 + j];
        const float bin = b_ih[8 + j];

        const f32x4* xrow = (const f32x4*)x + ((size_t)b * T_STEPS) * 4 + j;
        const int half = (wid - 1) * 16;     // producer 1: steps 0..15, producer 2: 16..31

        produce16(0 * CHUNK + half, xrow, ring, lane, wr4, wz4, wn4, br, bz, bin);
        __syncthreads();                      // chunk 0 ready
#pragma unroll 1
        for (int k = 0; k < NCH; ++k) {
            if (k + 1 < NCH)                  // uniform branch, no barrier inside
                produce16((k + 1) * CHUNK + half, xrow, ring, lane,
                          wr4, wz4, wn4, br, bz, bin);
            __syncthreads();                  // matches consumer's per-chunk barrier
        }
    }
}

extern "C" void kernel_launch(void* const* d_in, const int* in_sizes, int n_in,
                              void* d_out, int out_size, void* d_ws, size_t ws_size,
                              hipStream_t stream) {
    const float* x    = (const float*)d_in[0];
    const float* w_ih = (const float*)d_in[1];
    const float* w_hh = (const float*)d_in[2];
    const float* b_ih = (const float*)d_in[3];
    const float* b_hh = (const float*)d_in[4];
    const float* fc_w = (const float*)d_in[5];
    const float* fc_b = (const float*)d_in[6];
    float* out = (float*)d_out;

    const int B = out_size;      // 4096
    const int grid = B / 16;     // 16 batch rows per block, 3 waves per block
    gru_pc_kernel<<<grid, 192, 0, stream>>>(x, w_ih, w_hh, b_ih, b_hh, fc_w, fc_b, out);
}